// Round 1
// baseline (479.077 us; speedup 1.0000x reference)
//
#include <hip/hip_runtime.h>
#include <math.h>

// Problem: B=4096, T=256, D=64
//   mats[t] = expm(kernel * time[t])            (T x D x D)
//   out[b,t,i] = sum_j mats[t,i,j] * x0[b,j]    x0 = inputs[:,0,:]
//
// Phase 1: one WG per t computes expm via scaling-and-squaring + Taylor(10),
//          writes G[t][j][i] = mats[t][i][j] (transposed) into d_ws (4 MB).
// Phase 2: one WG per (t, 64-batch tile): C(64b x 64i) = X0 * G[t],
//          4x4 register tile per thread, both LDS operand reads are b128.

#define TT 256
#define DD 64
#define BB 4096
#define S1 68           // padded LDS row stride (words); 68*4=272B, 16B-aligned rows
#define THETA 0.5f
#define MTERMS 10

// C[i][j] = f * sum_k Lt[k*S1+i] * R[k*S1+j]   (i.e. C = Lt^T * R, both stride S1)
// optional: Eacc[i][j] += C[i][j]
__device__ __forceinline__ void mm68(const float* __restrict__ Lt,
                                     const float* __restrict__ R,
                                     float* __restrict__ C,
                                     float f, float* __restrict__ Eacc, int tid) {
    const int i0 = (tid & 15) * 4;
    const int j0 = (tid >> 4) * 4;
    float acc[4][4];
#pragma unroll
    for (int r = 0; r < 4; ++r)
#pragma unroll
        for (int c = 0; c < 4; ++c) acc[r][c] = 0.f;

#pragma unroll 8
    for (int k = 0; k < 64; ++k) {
        const float4 a = *reinterpret_cast<const float4*>(&Lt[k * S1 + i0]);
        const float4 b = *reinterpret_cast<const float4*>(&R[k * S1 + j0]);
        const float av[4] = {a.x, a.y, a.z, a.w};
        const float bv[4] = {b.x, b.y, b.z, b.w};
#pragma unroll
        for (int r = 0; r < 4; ++r)
#pragma unroll
            for (int c = 0; c < 4; ++c) acc[r][c] = fmaf(av[r], bv[c], acc[r][c]);
    }

#pragma unroll
    for (int r = 0; r < 4; ++r) {
        float4 v;
        v.x = acc[r][0] * f; v.y = acc[r][1] * f; v.z = acc[r][2] * f; v.w = acc[r][3] * f;
        *reinterpret_cast<float4*>(&C[(i0 + r) * S1 + j0]) = v;
        if (Eacc) {
            float* e = &Eacc[(i0 + r) * S1 + j0];
            e[0] += v.x; e[1] += v.y; e[2] += v.z; e[3] += v.w;
        }
    }
}

// XT = X^T (both stride S1)
__device__ __forceinline__ void transpose68(const float* __restrict__ X,
                                            float* __restrict__ XT, int tid) {
    const int i = tid >> 2;
    const int j0 = (tid & 3) * 16;
#pragma unroll
    for (int c4 = 0; c4 < 4; ++c4) {
        const float4 v = *reinterpret_cast<const float4*>(&X[i * S1 + j0 + 4 * c4]);
        XT[(j0 + 4 * c4 + 0) * S1 + i] = v.x;
        XT[(j0 + 4 * c4 + 1) * S1 + i] = v.y;
        XT[(j0 + 4 * c4 + 2) * S1 + i] = v.z;
        XT[(j0 + 4 * c4 + 3) * S1 + i] = v.w;
    }
}

__global__ __launch_bounds__(256)
void expm_kernel(const float* __restrict__ K, const float* __restrict__ tim,
                 float* __restrict__ G) {
    __shared__ float As[64 * S1];
    __shared__ float Pa[64 * S1];
    __shared__ float Pb[64 * S1];
    __shared__ float Et[64 * S1];
    __shared__ float Tx[64 * S1];
    __shared__ float red[64];

    const int tid = threadIdx.x;
    const int t = blockIdx.x;
    const float tval = tim[t];

    // inf-norm of K (rows of |K| summed, max)
    if (tid < 64) {
        float s = 0.f;
        for (int j = 0; j < 64; ++j) s += fabsf(K[tid * 64 + j]);
        red[tid] = s;
    }
    __syncthreads();
    if (tid == 0) {
        float m = 0.f;
        for (int i = 0; i < 64; ++i) m = fmaxf(m, red[i]);
        const float nt = m * tval;
        int s = 0;
        if (nt > THETA) {
            s = (int)ceilf(log2f(nt / THETA));
            if (s < 0) s = 0;
        }
        red[0] = ldexpf(tval, -s);   // scale = t / 2^s
        red[1] = (float)s;
    }
    __syncthreads();
    const float scale = red[0];
    const int sq = (int)red[1];
    __syncthreads();

    // As = K*scale ; Pa = As^T (=P1^T) ; Et = I + As^T (=E^T after 1 term)
    {
        const int i = tid >> 2;
        const int j0 = (tid & 3) * 16;
#pragma unroll
        for (int c = 0; c < 16; ++c) {
            const int j = j0 + c;
            const float v = K[i * 64 + j] * scale;
            As[i * S1 + j] = v;
            Pa[j * S1 + i] = v;
            Et[j * S1 + i] = v + ((i == j) ? 1.f : 0.f);
        }
    }
    __syncthreads();

    // Taylor: P_n^T = (1/n) * As^T * P_{n-1}^T ; E^T += P_n^T
    float* Pcur = Pa;
    float* Pnext = Pb;
    for (int n = 2; n <= MTERMS; ++n) {
        mm68(As, Pcur, Pnext, 1.0f / (float)n, Et, tid);
        __syncthreads();
        float* tmp = Pcur; Pcur = Pnext; Pnext = tmp;
    }

    // Squaring: cur = E; repeat sq times: cur = cur*cur
    transpose68(Et, Tx, tid);     // Tx = E
    __syncthreads();
    float* cur = Tx;
    float* nxt = Pa;
    const float* curT = Et;       // Et == cur^T for round 0
    for (int r = 0; r < sq; ++r) {
        if (r > 0) {
            transpose68(cur, Pb, tid);
            __syncthreads();
            curT = Pb;
        }
        mm68(curT, cur, nxt, 1.f, nullptr, tid);
        __syncthreads();
        float* tmp = cur; cur = nxt; nxt = tmp;
    }

    // G[t][j][i] = cur[i][j]  (store mats[t] transposed, coalesced global writes)
    {
        const int j = tid >> 2;
        const int i0 = (tid & 3) * 16;
        float* outp = G + (size_t)t * 4096 + j * 64 + i0;
#pragma unroll
        for (int c4 = 0; c4 < 4; ++c4) {
            float4 v;
            v.x = cur[(i0 + 4 * c4 + 0) * S1 + j];
            v.y = cur[(i0 + 4 * c4 + 1) * S1 + j];
            v.z = cur[(i0 + 4 * c4 + 2) * S1 + j];
            v.w = cur[(i0 + 4 * c4 + 3) * S1 + j];
            *reinterpret_cast<float4*>(outp + 4 * c4) = v;
        }
    }
}

__global__ __launch_bounds__(256)
void traj_kernel(const float* __restrict__ inputs, const float* __restrict__ G,
                 float* __restrict__ out) {
    __shared__ float MT[64 * 64];    // G[t][k][i], stride 64
    __shared__ float X0T[64 * S1];   // x0 tile transposed: X0T[k][b], stride 68

    const int tid = threadIdx.x;
    const int t = blockIdx.x & (TT - 1);
    const int b0 = (blockIdx.x >> 8) * 64;

    // stage G[t] (16 KB, contiguous)
    {
        const float4* src = reinterpret_cast<const float4*>(G) + (size_t)t * 1024;
        float4* dst = reinterpret_cast<float4*>(MT);
#pragma unroll
        for (int c = 0; c < 4; ++c) dst[tid + 256 * c] = src[tid + 256 * c];
    }
    // stage x0 tile transposed: x0[b][j] = inputs[b*T*D + j]
    {
        const int bb = tid >> 2;
        const int j0 = (tid & 3) * 16;
        const float* src = inputs + (size_t)(b0 + bb) * (TT * DD) + j0;
#pragma unroll
        for (int c4 = 0; c4 < 4; ++c4) {
            const float4 v = *reinterpret_cast<const float4*>(src + 4 * c4);
            X0T[(j0 + 4 * c4 + 0) * S1 + bb] = v.x;
            X0T[(j0 + 4 * c4 + 1) * S1 + bb] = v.y;
            X0T[(j0 + 4 * c4 + 2) * S1 + bb] = v.z;
            X0T[(j0 + 4 * c4 + 3) * S1 + bb] = v.w;
        }
    }
    __syncthreads();

    const int n0 = (tid & 15) * 4;   // i  (coalesced store dimension)
    const int m0 = (tid >> 4) * 4;   // b within tile
    float acc[4][4];
#pragma unroll
    for (int r = 0; r < 4; ++r)
#pragma unroll
        for (int c = 0; c < 4; ++c) acc[r][c] = 0.f;

#pragma unroll 8
    for (int k = 0; k < 64; ++k) {
        const float4 a = *reinterpret_cast<const float4*>(&X0T[k * S1 + m0]);
        const float4 b = *reinterpret_cast<const float4*>(&MT[k * 64 + n0]);
        const float av[4] = {a.x, a.y, a.z, a.w};
        const float bv[4] = {b.x, b.y, b.z, b.w};
#pragma unroll
        for (int r = 0; r < 4; ++r)
#pragma unroll
            for (int c = 0; c < 4; ++c) acc[r][c] = fmaf(av[r], bv[c], acc[r][c]);
    }

    // out[b0+m0+r][t][n0..n0+3]
    float* dst = out + (size_t)(b0 + m0) * (TT * DD) + (size_t)t * DD + n0;
#pragma unroll
    for (int r = 0; r < 4; ++r) {
        float4 v;
        v.x = acc[r][0]; v.y = acc[r][1]; v.z = acc[r][2]; v.w = acc[r][3];
        *reinterpret_cast<float4*>(dst + (size_t)r * (TT * DD)) = v;
    }
}

extern "C" void kernel_launch(void* const* d_in, const int* in_sizes, int n_in,
                              void* d_out, int out_size, void* d_ws, size_t ws_size,
                              hipStream_t stream) {
    const float* inputs = (const float*)d_in[0];
    const float* tim    = (const float*)d_in[1];
    const float* K      = (const float*)d_in[2];
    float* out = (float*)d_out;
    float* G   = (float*)d_ws;   // T*D*D floats = 4 MB of scratch

    expm_kernel<<<TT, 256, 0, stream>>>(K, tim, G);
    traj_kernel<<<(BB / 64) * TT, 256, 0, stream>>>(inputs, G, out);
}

// Round 2
// 440.845 us; speedup vs baseline: 1.0867x; 1.0867x over previous
//
#include <hip/hip_runtime.h>
#include <math.h>

// Problem: B=4096, T=256, D=64
//   mats[t] = expm(kernel * time[t])            (T x D x D)
//   out[b,t,i] = sum_j mats[t,i,j] * x0[b,j]    x0 = inputs[:,0,:]
//
// Phase 1 (expm_kernel): one WG per t, scaling-and-squaring + Taylor(10),
//   writes G[t][i][j] = mats[t][i][j] (natural layout) into d_ws (4 MB).
// Phase 2 (traj_mfma): one WG per (t, 64-batch tile). C(64b x 64i) via
//   MFMA 16x16x32 bf16 with 2-term hi/lo split (3 products): the K=64
//   contraction runs on the matrix pipe instead of the LDS/VALU path.

#define TT 256
#define DD 64
#define BB 4096
#define S1 68           // fp32 LDS row stride (words) for expm
#define LD 72           // bf16 LDS row stride (elements) for traj; 144 B, 16B-aligned
#define THETA 0.5f
#define MTERMS 10

typedef __attribute__((ext_vector_type(8))) short short8;
typedef __attribute__((ext_vector_type(4))) float f32x4;

// ---------------- expm phase ----------------

// C[i][j] = f * sum_k Lt[k*S1+i] * R[k*S1+j]   (C = Lt^T * R, all stride S1)
__device__ __forceinline__ void mm68(const float* __restrict__ Lt,
                                     const float* __restrict__ R,
                                     float* __restrict__ C,
                                     float f, float* __restrict__ Eacc, int tid) {
    const int i0 = (tid & 15) * 4;
    const int j0 = (tid >> 4) * 4;
    float acc[4][4];
#pragma unroll
    for (int r = 0; r < 4; ++r)
#pragma unroll
        for (int c = 0; c < 4; ++c) acc[r][c] = 0.f;

#pragma unroll 8
    for (int k = 0; k < 64; ++k) {
        const float4 a = *reinterpret_cast<const float4*>(&Lt[k * S1 + i0]);
        const float4 b = *reinterpret_cast<const float4*>(&R[k * S1 + j0]);
        const float av[4] = {a.x, a.y, a.z, a.w};
        const float bv[4] = {b.x, b.y, b.z, b.w};
#pragma unroll
        for (int r = 0; r < 4; ++r)
#pragma unroll
            for (int c = 0; c < 4; ++c) acc[r][c] = fmaf(av[r], bv[c], acc[r][c]);
    }

#pragma unroll
    for (int r = 0; r < 4; ++r) {
        float4 v;
        v.x = acc[r][0] * f; v.y = acc[r][1] * f; v.z = acc[r][2] * f; v.w = acc[r][3] * f;
        *reinterpret_cast<float4*>(&C[(i0 + r) * S1 + j0]) = v;
        if (Eacc) {
            float* e = &Eacc[(i0 + r) * S1 + j0];
            e[0] += v.x; e[1] += v.y; e[2] += v.z; e[3] += v.w;
        }
    }
}

__device__ __forceinline__ void transpose68(const float* __restrict__ X,
                                            float* __restrict__ XT, int tid) {
    const int i = tid >> 2;
    const int j0 = (tid & 3) * 16;
#pragma unroll
    for (int c4 = 0; c4 < 4; ++c4) {
        const float4 v = *reinterpret_cast<const float4*>(&X[i * S1 + j0 + 4 * c4]);
        XT[(j0 + 4 * c4 + 0) * S1 + i] = v.x;
        XT[(j0 + 4 * c4 + 1) * S1 + i] = v.y;
        XT[(j0 + 4 * c4 + 2) * S1 + i] = v.z;
        XT[(j0 + 4 * c4 + 3) * S1 + i] = v.w;
    }
}

__global__ __launch_bounds__(256)
void expm_kernel(const float* __restrict__ K, const float* __restrict__ tim,
                 float* __restrict__ G) {
    __shared__ float As[64 * S1];
    __shared__ float Pa[64 * S1];
    __shared__ float Pb[64 * S1];
    __shared__ float Et[64 * S1];
    __shared__ float Tx[64 * S1];
    __shared__ float red[64];

    const int tid = threadIdx.x;
    const int t = blockIdx.x;
    const float tval = tim[t];

    if (tid < 64) {
        float s = 0.f;
        for (int j = 0; j < 64; ++j) s += fabsf(K[tid * 64 + j]);
        red[tid] = s;
    }
    __syncthreads();
    if (tid == 0) {
        float m = 0.f;
        for (int i = 0; i < 64; ++i) m = fmaxf(m, red[i]);
        const float nt = m * tval;
        int s = 0;
        if (nt > THETA) {
            s = (int)ceilf(log2f(nt / THETA));
            if (s < 0) s = 0;
        }
        red[0] = ldexpf(tval, -s);
        red[1] = (float)s;
    }
    __syncthreads();
    const float scale = red[0];
    const int sq = (int)red[1];
    __syncthreads();

    // As = K*scale ; Pa = As^T (=P1^T) ; Et = I^T + As^T
    {
        const int i = tid >> 2;
        const int j0 = (tid & 3) * 16;
#pragma unroll
        for (int c = 0; c < 16; ++c) {
            const int j = j0 + c;
            const float v = K[i * 64 + j] * scale;
            As[i * S1 + j] = v;
            Pa[j * S1 + i] = v;
            Et[j * S1 + i] = v + ((i == j) ? 1.f : 0.f);
        }
    }
    __syncthreads();

    float* Pcur = Pa;
    float* Pnext = Pb;
    for (int n = 2; n <= MTERMS; ++n) {
        mm68(As, Pcur, Pnext, 1.0f / (float)n, Et, tid);
        __syncthreads();
        float* tmp = Pcur; Pcur = Pnext; Pnext = tmp;
    }

    transpose68(Et, Tx, tid);     // Tx = E (row-major [i][j])
    __syncthreads();
    float* cur = Tx;
    float* nxt = Pa;
    const float* curT = Et;
    for (int r = 0; r < sq; ++r) {
        if (r > 0) {
            transpose68(cur, Pb, tid);
            __syncthreads();
            curT = Pb;
        }
        mm68(curT, cur, nxt, 1.f, nullptr, tid);
        __syncthreads();
        float* tmp = cur; cur = nxt; nxt = tmp;
    }

    // G[t][i][j] = cur[i][j]  (natural mats layout, coalesced float4 writes)
    {
        const int i = tid >> 2;
        const int j0 = (tid & 3) * 16;
        float* outp = G + (size_t)t * 4096 + i * 64 + j0;
#pragma unroll
        for (int c4 = 0; c4 < 4; ++c4) {
            *reinterpret_cast<float4*>(outp + 4 * c4) =
                *reinterpret_cast<const float4*>(&cur[i * S1 + j0 + 4 * c4]);
        }
    }
}

// ---------------- traj phase (MFMA) ----------------

// split fp32 into bf16 hi (RN) + bf16 lo (trunc of residual); x ~ hi+lo, |eps|<~2^-17|x|
__device__ __forceinline__ void bf16_split(float x, unsigned short& hi, unsigned short& lo) {
    union { float f; unsigned int u; } a; a.f = x;
    unsigned int r = (a.u + 0x7fffu + ((a.u >> 16) & 1u)) & 0xffff0000u;  // RN to bf16
    hi = (unsigned short)(r >> 16);
    union { float f; unsigned int u; } d; d.f = x - __uint_as_float(r);
    lo = (unsigned short)(d.u >> 16);  // truncation of residual
}

__global__ __launch_bounds__(256)
void traj_mfma(const float* __restrict__ inputs, const float* __restrict__ G,
               float* __restrict__ out) {
    __shared__ unsigned short Ahi[64 * LD];  // x0 tile  [b][k]
    __shared__ unsigned short Alo[64 * LD];
    __shared__ unsigned short Bhi[64 * LD];  // mats     [i][k] (B^T layout for b-frag)
    __shared__ unsigned short Blo[64 * LD];

    const int tid = threadIdx.x;
    const int t  = blockIdx.x & (TT - 1);
    const int b0 = (blockIdx.x >> 8) * 64;

    // stage + convert: thread handles 16 consecutive elements of each tile
    {
        const int row  = tid >> 2;
        const int col0 = (tid & 3) * 16;
        const float* asrc = inputs + (size_t)(b0 + row) * (TT * DD) + col0;  // x0[b][j]
        const float* bsrc = G + (size_t)t * 4096 + row * 64 + col0;          // mats[i][j]
#pragma unroll
        for (int c = 0; c < 4; ++c) {
            const float4 va = *reinterpret_cast<const float4*>(asrc + 4 * c);
            const float4 vb = *reinterpret_cast<const float4*>(bsrc + 4 * c);
            ushort4 ah, al, bh, bl;
            bf16_split(va.x, ah.x, al.x); bf16_split(va.y, ah.y, al.y);
            bf16_split(va.z, ah.z, al.z); bf16_split(va.w, ah.w, al.w);
            bf16_split(vb.x, bh.x, bl.x); bf16_split(vb.y, bh.y, bl.y);
            bf16_split(vb.z, bh.z, bl.z); bf16_split(vb.w, bh.w, bl.w);
            const int o = row * LD + col0 + 4 * c;
            *reinterpret_cast<ushort4*>(&Ahi[o]) = ah;
            *reinterpret_cast<ushort4*>(&Alo[o]) = al;
            *reinterpret_cast<ushort4*>(&Bhi[o]) = bh;
            *reinterpret_cast<ushort4*>(&Blo[o]) = bl;
        }
    }
    __syncthreads();

    const int w  = tid >> 6;        // wave id: b rows [w*16, w*16+16)
    const int ln = tid & 15;        // lane&15
    const int qd = (tid >> 4) & 3;  // lane quad

    f32x4 acc[4];
#pragma unroll
    for (int nt = 0; nt < 4; ++nt) acc[nt] = (f32x4){0.f, 0.f, 0.f, 0.f};

#pragma unroll
    for (int kh = 0; kh < 2; ++kh) {
        const int ko = kh * 32 + qd * 8;
        const short8 ah = *reinterpret_cast<const short8*>(&Ahi[(w * 16 + ln) * LD + ko]);
        const short8 al = *reinterpret_cast<const short8*>(&Alo[(w * 16 + ln) * LD + ko]);
#pragma unroll
        for (int nt = 0; nt < 4; ++nt) {
            const short8 bh = *reinterpret_cast<const short8*>(&Bhi[(nt * 16 + ln) * LD + ko]);
            const short8 bl = *reinterpret_cast<const short8*>(&Blo[(nt * 16 + ln) * LD + ko]);
            acc[nt] = __builtin_amdgcn_mfma_f32_16x16x32_bf16(ah, bh, acc[nt], 0, 0, 0);
            acc[nt] = __builtin_amdgcn_mfma_f32_16x16x32_bf16(ah, bl, acc[nt], 0, 0, 0);
            acc[nt] = __builtin_amdgcn_mfma_f32_16x16x32_bf16(al, bh, acc[nt], 0, 0, 0);
        }
    }

    // D[m=b within 16][n=i]: lane holds D[qd*4+r][ln] per nt tile
    float* obase = out + (size_t)(b0 + w * 16 + qd * 4) * (TT * DD) + (size_t)t * DD + ln;
#pragma unroll
    for (int r = 0; r < 4; ++r) {
#pragma unroll
        for (int nt = 0; nt < 4; ++nt) {
            obase[(size_t)r * (TT * DD) + nt * 16] = acc[nt][r];
        }
    }
}

extern "C" void kernel_launch(void* const* d_in, const int* in_sizes, int n_in,
                              void* d_out, int out_size, void* d_ws, size_t ws_size,
                              hipStream_t stream) {
    const float* inputs = (const float*)d_in[0];
    const float* tim    = (const float*)d_in[1];
    const float* K      = (const float*)d_in[2];
    float* out = (float*)d_out;
    float* G   = (float*)d_ws;   // T*D*D floats = 4 MB of scratch

    expm_kernel<<<TT, 256, 0, stream>>>(K, tim, G);
    traj_mfma<<<(BB / 64) * TT, 256, 0, stream>>>(inputs, G, out);
}